// Round 12
// baseline (343.056 us; speedup 1.0000x reference)
//
#include <hip/hip_runtime.h>

// NLinearMemoryEfficient: out[b,n,o] = sum_i x[b,n,i]*W[n,o,i] + bias[n,o]
// B=8192, N=256, D_IN=64, D_OUT=128, fp32 in/out. bf16 MFMA (thr 7.09e-2).
//
// r12 = r11 (310.6us) + LDS ALIASING for occupancy. ONE structural change:
// the store patch now lives INSIDE xfrag (they are never live at the same
// time: xfrag is consumed by the MFMA phase; one extra raw barrier after
// the MFMAs makes the region safe for the epilogue). LDS 48->32 KB and
// __launch_bounds__(256,4) (VGPR cap 128) -> 4 blocks/CU = 16 waves/CU
// (+33% memory parallelism; the r8/r9 stall probes were neutral at FIXED
// occupancy - this raises outstanding requests per CU instead).
//
// Everything else IDENTICAL to r11: n-fastest dispatch order (r10 +9%),
// nontemporal x loads / out stores (r11 -2%), raw lgkmcnt-only barriers,
// reg prefetch 1 tile ahead, k-permuted swizzled xfrag pack (conflict-
// free), full-line 256B-per-row stores via swizzled patch (r4: partial
// lines cost 1.6x write amp), bias as ks=0 MFMA C-operand.

typedef short  short8  __attribute__((ext_vector_type(8)));
typedef float  float4v __attribute__((ext_vector_type(4)));

constexpr int NFEAT  = 256;
constexpr int DI     = 64;
constexpr int DO     = 128;
constexpr int TILE_B = 128;
constexpr int S      = 8;     // tiles per block

// raw barrier: LDS-visibility fence only, NO vmcnt drain
#define BAR_LDS()                                                   \
    do {                                                            \
        asm volatile("s_waitcnt lgkmcnt(0)" ::: "memory");          \
        __builtin_amdgcn_s_barrier();                               \
        asm volatile("" ::: "memory");                              \
    } while (0)

__device__ __forceinline__ uint32_t pack_bf16(float a, float b) {
    uint32_t ua = __builtin_bit_cast(uint32_t, a);
    uint32_t ub = __builtin_bit_cast(uint32_t, b);
    ua += 0x7fffu + ((ua >> 16) & 1u);   // RNE
    ub += 0x7fffu + ((ub >> 16) & 1u);
    return (ua >> 16) | (ub & 0xffff0000u);
}

__global__ __launch_bounds__(256, 4) void nlinear_mfma_r12_kernel(
    const float* __restrict__ x, const float* __restrict__ W,
    const float* __restrict__ bias, float* __restrict__ out)
{
    // W A-frags: [otile][ks][lane][slot] u32 (linear; reads conflict-free)
    __shared__ __align__(16) uint32_t wfrag[8][2][64][4];   // 16 KB
    // x B-frags / store patch (ALIASED - never live simultaneously):
    //  - as frags: [tile][512] u32, XOR-swizzled placement (16 KB)
    //  - as patch: wave wv owns floats [wv*1024, +1024) = [16][64] f32
    __shared__ __align__(16) uint32_t xfrag[8][512];        // 16 KB

    // n fastest in dispatch order: resident set covers all n of ~3 slabs.
    const int bid  = blockIdx.x;
    const int n    = bid & 255;        // 0..255, varies fastest
    const int slab = bid >> 8;         // 8 slabs of S*128 = 1024 rows
    const uint32_t b_base = (uint32_t)slab * (TILE_B * S);

    const int t   = threadIdx.x;
    const int l   = t & 63;
    const int wv  = t >> 6;
    const int wr  = wv >> 1;           // b-half (0..1)
    const int wc  = wv & 1;            // o-half (0..1)
    const int llo = l & 15;
    const int lhi = l >> 4;

    float* const patch_w = (float*)&xfrag[0][0] + wv * 1024;   // [16][64] f32

    // thread-constant pack decomposition: c = t&15 -> (ks,S,K); row r = t>>4
    const int c_ks = t & 1;
    const int c_S  = (t >> 1) & 1;
    const int c_K  = (t >> 2) & 3;
    const int rr   = t >> 4;           // row-in-tile
    const int Upak = ((c_ks << 6) | (c_K << 4) | rr) ^ ((c_K & 1) << 2) ^ (c_ks << 1);
    const int pak_off = Upak * 4 + c_S * 2;   // u32 offset within tile region

    // ---- stage W_n as bf16 A-fragments with the SAME k-permutation ----
    const float4* Wn4 = (const float4*)(W + (size_t)n * DO * DI);
#pragma unroll
    for (int p = 0; p < 8; ++p) {
        int idx  = p * 256 + t;        // o = idx>>4 = p*16 + (t>>4); cw = t&15
        float4 f = Wn4[idx];
        int o    = idx >> 4;
        int lane = (c_K << 4) | (o & 15);
        uint2 pk = make_uint2(pack_bf16(f.x, f.y), pack_bf16(f.z, f.w));
        *(uint2*)&wfrag[o >> 4][c_ks][lane][c_S * 2] = pk;
    }

    // bias: 4 consecutive o per lane -> C operand of ks=0 MFMA
    float4v bias4[4];
#pragma unroll
    for (int ot = 0; ot < 4; ++ot)
        bias4[ot] = *(const float4v*)&bias[n * DO + wc * 64 + ot * 16 + lhi * 4];

    // frag-read base offsets (u32) for the two ks, thread-constant
    const int rd0 = (((0 << 6) | l) ^ (((l >> 4) & 1) << 2) ^ 0) * 4;
    const int rd1 = (((1 << 6) | l) ^ (((l >> 4) & 1) << 2) ^ 2) * 4;

    const float4v* Xg4 = (const float4v*)x;
    float4v xr[8];

#define LOADX(JT)                                                   \
    _Pragma("unroll")                                               \
    for (int p = 0; p < 8; ++p) {                                   \
        int idx = p * 256 + t;                                      \
        uint32_t b = b_base + (uint32_t)(JT) * TILE_B + (idx >> 4); \
        xr[p] = __builtin_nontemporal_load(                         \
                    &Xg4[b * 4096u + n * 16u + (idx & 15)]);        \
    }

    LOADX(0);

    for (int j = 0; j < S; ++j) {
        BAR_LDS();                     // all waves done with epilogue(j-1) region

        // pack tile j regs -> swizzled frags (thread-constant addresses,
        // each bank touched exactly twice per instruction)
#pragma unroll
        for (int p = 0; p < 8; ++p) {
            uint2 pk = make_uint2(pack_bf16(xr[p][0], xr[p][1]),
                                  pack_bf16(xr[p][2], xr[p][3]));
            *(uint2*)&xfrag[p][pak_off] = pk;
        }
        if (j + 1 < S) { LOADX(j + 1); }   // full tile of latency ahead

        BAR_LDS();                     // xfrag ready (lgkmcnt(0) before bar)

        // ---- compute: D(o,b) = W_n * x^T + bias ----
        float4v acc[4][4];
#pragma unroll
        for (int ks = 0; ks < 2; ++ks) {
            short8 wf[4];
#pragma unroll
            for (int ot = 0; ot < 4; ++ot)
                wf[ot] = *(const short8*)&wfrag[wc * 4 + ot][ks][l][0];
#pragma unroll
            for (int bt = 0; bt < 4; ++bt) {
                short8 xf = *(const short8*)&xfrag[wr * 4 + bt][ks ? rd1 : rd0];
#pragma unroll
                for (int ot = 0; ot < 4; ++ot) {
                    acc[bt][ot] = __builtin_amdgcn_mfma_f32_16x16x32_bf16(
                        wf[ot], xf, (ks == 0) ? bias4[ot] : acc[bt][ot], 0, 0, 0);
                }
            }
        }

        BAR_LDS();                     // all frag reads done -> region = patch

        // ---- full-line store epilogue (wave-private patch inside xfrag) --
        // acc[bt][ot][reg]: row b = ..bt*16+llo, o = wc*64 + ot*16 + lhi*4+reg
#pragma unroll
        for (int bt = 0; bt < 4; ++bt) {
#pragma unroll
            for (int ot = 0; ot < 4; ++ot)
                *(float4v*)&patch_w[llo * 64 + (((ot * 4 + lhi) ^ (llo & 7)) * 4)]
                    = acc[bt][ot];
            // read row-major: 16 lanes cover one row's 256B (2 full lines)
#pragma unroll
            for (int m = 0; m < 4; ++m) {
                int R = m * 4 + lhi;
                float4v v = *(const float4v*)&patch_w[R * 64 + ((llo ^ (R & 7)) * 4)];
                uint32_t b = b_base + (uint32_t)j * TILE_B + wr * 64
                           + bt * 16 + (uint32_t)R;
                __builtin_nontemporal_store(
                    v, (float4v*)&out[b * 32768u + n * 128u + wc * 64u + llo * 4u]);
            }
        }
    }
#undef LOADX
}

extern "C" void kernel_launch(void* const* d_in, const int* in_sizes, int n_in,
                              void* d_out, int out_size, void* d_ws, size_t ws_size,
                              hipStream_t stream) {
    const float* xp = (const float*)d_in[0];
    const float* Wp = (const float*)d_in[1];
    const float* bp = (const float*)d_in[2];
    float* op = (float*)d_out;

    dim3 grid(2048);   // 256 n (fastest) * 8 slabs
    dim3 block(256);
    hipLaunchKernelGGL(nlinear_mfma_r12_kernel, grid, block, 0, stream, xp, Wp, bp, op);
}

// Round 13
// 306.819 us; speedup vs baseline: 1.1181x; 1.1181x over previous
//
#include <hip/hip_runtime.h>

// NLinearMemoryEfficient: out[b,n,o] = sum_i x[b,n,i]*W[n,o,i] + bias[n,o]
// B=8192, N=256, D_IN=64, D_OUT=128, fp32 in/out. bf16 MFMA (thr 7.09e-2).
//
// r13 = r11 (310.6us, best) with TILE_B 128->64: clean occupancy probe.
// LDS = wfrag 16K + xfrag 8K + patch 16K = 40KB -> 4 blocks/CU = 16
// waves/CU (+33% memory parallelism). Register pressure halves (acc 32,
// xr 16 -> ~95 VGPR, no spill at the (256,4) cap). r12's regression was
// confounded (3rd barrier + probable spill at 130-live/128-cap); this
// keeps r11's EXACT 2-barrier structure and all proven elements:
// n-fastest dispatch order (r10 +9%), nontemporal x loads / out stores
// (r11 -2%), raw lgkmcnt-only barriers (stores stream across), reg
// prefetch 1 tile ahead, k-permuted swizzled xfrag pack (conflict-free),
// full-line 256B-per-row stores via swizzled patch (r4: partial lines
// cost 1.6x write amp), bias as ks=0 MFMA C-operand.
//
// Per tile (64 rows): wave (wr,wc) computes bt in {wr*2,wr*2+1} (16 rows
// each) x o-half wc. Pack: thread t's chunk p (=bt) lands at a thread-
// constant swizzled address (same formula as r11; per-wave bank pattern
// unchanged -> 2 touches/bank).

typedef short  short8  __attribute__((ext_vector_type(8)));
typedef float  float4v __attribute__((ext_vector_type(4)));

constexpr int NFEAT  = 256;
constexpr int DI     = 64;
constexpr int DO     = 128;
constexpr int TILE_B = 64;
constexpr int S      = 16;    // tiles per block (1024 rows)

// raw barrier: LDS-visibility fence only, NO vmcnt drain
#define BAR_LDS()                                                   \
    do {                                                            \
        asm volatile("s_waitcnt lgkmcnt(0)" ::: "memory");          \
        __builtin_amdgcn_s_barrier();                               \
        asm volatile("" ::: "memory");                              \
    } while (0)

__device__ __forceinline__ uint32_t pack_bf16(float a, float b) {
    uint32_t ua = __builtin_bit_cast(uint32_t, a);
    uint32_t ub = __builtin_bit_cast(uint32_t, b);
    ua += 0x7fffu + ((ua >> 16) & 1u);   // RNE
    ub += 0x7fffu + ((ub >> 16) & 1u);
    return (ua >> 16) | (ub & 0xffff0000u);
}

__global__ __launch_bounds__(256, 4) void nlinear_mfma_r13_kernel(
    const float* __restrict__ x, const float* __restrict__ W,
    const float* __restrict__ bias, float* __restrict__ out)
{
    // W A-frags: [otile][ks][lane][slot] u32 (linear; reads conflict-free)
    __shared__ __align__(16) uint32_t wfrag[8][2][64][4];   // 16 KB
    // x B-frags: [bt][512] u32, XOR-swizzled placement (8 KB)
    __shared__ __align__(16) uint32_t xfrag[4][512];        //  8 KB
    // store patch: stride 64 + XOR unit swizzle (separate, r11-style)
    __shared__ __align__(16) float    patch[4][16][64];     // 16 KB

    // n fastest in dispatch order: resident set covers all n of ~slabs.
    const int bid  = blockIdx.x;
    const int n    = bid & 255;        // 0..255, varies fastest
    const int slab = bid >> 8;         // 8 slabs of S*64 = 1024 rows
    const uint32_t b_base = (uint32_t)slab * (TILE_B * S);

    const int t   = threadIdx.x;
    const int l   = t & 63;
    const int wv  = t >> 6;
    const int wr  = wv >> 1;           // b-half (0..1): bt = wr*2 + {0,1}
    const int wc  = wv & 1;            // o-half (0..1)
    const int llo = l & 15;
    const int lhi = l >> 4;

    // thread-constant pack decomposition: c = t&15 -> (ks,S,K); row = t>>4
    const int c_ks = t & 1;
    const int c_S  = (t >> 1) & 1;
    const int c_K  = (t >> 2) & 3;
    const int Upak = ((c_ks << 6) | (c_K << 4) | (t >> 4))
                   ^ ((c_K & 1) << 2) ^ (c_ks << 1);
    const int pak_off = Upak * 4 + c_S * 2;   // u32 offset within bt region

    // ---- stage W_n as bf16 A-fragments with the SAME k-permutation ----
    const float4* Wn4 = (const float4*)(W + (size_t)n * DO * DI);
#pragma unroll
    for (int p = 0; p < 8; ++p) {
        int idx  = p * 256 + t;        // o = idx>>4 = p*16 + (t>>4)
        float4 f = Wn4[idx];
        int o    = idx >> 4;
        int lane = (c_K << 4) | (o & 15);
        uint2 pk = make_uint2(pack_bf16(f.x, f.y), pack_bf16(f.z, f.w));
        *(uint2*)&wfrag[o >> 4][c_ks][lane][c_S * 2] = pk;
    }

    // bias: 4 consecutive o per lane -> C operand of ks=0 MFMA
    float4v bias4[4];
#pragma unroll
    for (int ot = 0; ot < 4; ++ot)
        bias4[ot] = *(const float4v*)&bias[n * DO + wc * 64 + ot * 16 + lhi * 4];

    // frag-read base offsets (u32) for the two ks, thread-constant
    const int rd0 = (((0 << 6) | l) ^ (((l >> 4) & 1) << 2) ^ 0) * 4;
    const int rd1 = (((1 << 6) | l) ^ (((l >> 4) & 1) << 2) ^ 2) * 4;

    const float4v* Xg4 = (const float4v*)x;
    float4v xr[4];

#define LOADX(JT)                                                   \
    _Pragma("unroll")                                               \
    for (int p = 0; p < 4; ++p) {                                   \
        int idx = p * 256 + t;       /* row = idx>>4 in 0..63 */    \
        uint32_t b = b_base + (uint32_t)(JT) * TILE_B + (idx >> 4); \
        xr[p] = __builtin_nontemporal_load(                         \
                    &Xg4[b * 4096u + n * 16u + (idx & 15)]);        \
    }

    LOADX(0);

    for (int j = 0; j < S; ++j) {
        BAR_LDS();                     // xfrag free (prev tile's reads consumed)

        // pack tile j regs -> swizzled frags (p = bt; thread-constant addr,
        // per-wave bank pattern = 2 touches/bank, same as r11)
#pragma unroll
        for (int p = 0; p < 4; ++p) {
            uint2 pk = make_uint2(pack_bf16(xr[p][0], xr[p][1]),
                                  pack_bf16(xr[p][2], xr[p][3]));
            *(uint2*)&xfrag[p][pak_off] = pk;
        }
        if (j + 1 < S) { LOADX(j + 1); }   // one tile body of latency ahead

        BAR_LDS();                     // xfrag ready (lgkmcnt(0) before bar)

        // ---- compute: D(o,b) = W_n * x^T + bias ----
        float4v acc[2][4];
#pragma unroll
        for (int ks = 0; ks < 2; ++ks) {
            short8 wf[4];
#pragma unroll
            for (int ot = 0; ot < 4; ++ot)
                wf[ot] = *(const short8*)&wfrag[wc * 4 + ot][ks][l][0];
#pragma unroll
            for (int bt = 0; bt < 2; ++bt) {
                short8 xf = *(const short8*)&xfrag[wr * 2 + bt][ks ? rd1 : rd0];
#pragma unroll
                for (int ot = 0; ot < 4; ++ot) {
                    acc[bt][ot] = __builtin_amdgcn_mfma_f32_16x16x32_bf16(
                        wf[ot], xf, (ks == 0) ? bias4[ot] : acc[bt][ot], 0, 0, 0);
                }
            }
        }

        // ---- full-line store epilogue (swizzled patch, conflict-free) ----
        // acc[bt][ot][reg]: row b = ..(wr*2+bt)*16+llo, o = wc*64+ot*16+lhi*4+reg
#pragma unroll
        for (int bt = 0; bt < 2; ++bt) {
#pragma unroll
            for (int ot = 0; ot < 4; ++ot)
                *(float4v*)&patch[wv][llo][((ot * 4 + lhi) ^ (llo & 7)) * 4] = acc[bt][ot];
            // read row-major: 16 lanes cover one row's 256B (2 full lines)
#pragma unroll
            for (int m = 0; m < 4; ++m) {
                int R = m * 4 + lhi;
                float4v v = *(const float4v*)&patch[wv][R][(llo ^ (R & 7)) * 4];
                uint32_t b = b_base + (uint32_t)j * TILE_B
                           + (uint32_t)(wr * 2 + bt) * 16 + (uint32_t)R;
                __builtin_nontemporal_store(
                    v, (float4v*)&out[b * 32768u + n * 128u + wc * 64u + llo * 4u]);
            }
        }
    }
#undef LOADX
}

extern "C" void kernel_launch(void* const* d_in, const int* in_sizes, int n_in,
                              void* d_out, int out_size, void* d_ws, size_t ws_size,
                              hipStream_t stream) {
    const float* xp = (const float*)d_in[0];
    const float* Wp = (const float*)d_in[1];
    const float* bp = (const float*)d_in[2];
    float* op = (float*)d_out;

    dim3 grid(2048);   // 256 n (fastest) * 8 slabs of 1024 rows
    dim3 block(256);
    hipLaunchKernelGGL(nlinear_mfma_r13_kernel, grid, block, 0, stream, xp, Wp, bp, op);
}

// Round 14
// 306.254 us; speedup vs baseline: 1.1202x; 1.0018x over previous
//
#include <hip/hip_runtime.h>

// NLinearMemoryEfficient: out[b,n,o] = sum_i x[b,n,i]*W[n,o,i] + bias[n,o]
// B=8192, N=256, D_IN=64, D_OUT=128, fp32 in/out. bf16 MFMA (thr 7.09e-2).
//
// r14 = r13 (306.8us) + EXACTLY-RESIDENT GRID + DEPTH-2 PREFETCH.
//  - S=32 (2048 rows/block) -> grid = 1024 = 4 blocks/CU x 256 CU: whole
//    grid co-resident in ONE dispatch generation. Preamble (W stage/pack,
//    cold x load) paid once per CU slot instead of 8x. The 4 blocks
//    sharing W_n are bid,bid+256,.. -> same XCD -> W L2-local.
//  - Depth-2 register prefetch, statically-indexed double buffer
//    (named xrA/xrB, parity-switched): issue(j+2) -> consume distance =
//    2 full bodies >> 900cyc HBM latency.
//  - x tile-0/1 loads issued BEFORE W staging (cold-start latency hides
//    under the W pack).
// Everything else IDENTICAL to r13: TILE_B=64, 16 waves/CU (LDS 40KB,
// VGPR ~110 < 128 cap), n-fastest mapping (r10), nontemporal x/out
// (r11), raw lgkmcnt-only barriers (r9), k-permuted swizzled xfrag pack
// (conflict-free, r8), full-line 256B-per-row stores via swizzled patch
// (r5, fixes r4's 1.6x write amp), bias as ks=0 MFMA C-operand.

typedef short  short8  __attribute__((ext_vector_type(8)));
typedef float  float4v __attribute__((ext_vector_type(4)));

constexpr int NFEAT  = 256;
constexpr int DI     = 64;
constexpr int DO     = 128;
constexpr int TILE_B = 64;
constexpr int S      = 32;    // tiles per block (2048 rows)

// raw barrier: LDS-visibility fence only, NO vmcnt drain
#define BAR_LDS()                                                   \
    do {                                                            \
        asm volatile("s_waitcnt lgkmcnt(0)" ::: "memory");          \
        __builtin_amdgcn_s_barrier();                               \
        asm volatile("" ::: "memory");                              \
    } while (0)

__device__ __forceinline__ uint32_t pack_bf16(float a, float b) {
    uint32_t ua = __builtin_bit_cast(uint32_t, a);
    uint32_t ub = __builtin_bit_cast(uint32_t, b);
    ua += 0x7fffu + ((ua >> 16) & 1u);   // RNE
    ub += 0x7fffu + ((ub >> 16) & 1u);
    return (ua >> 16) | (ub & 0xffff0000u);
}

__global__ __launch_bounds__(256, 4) void nlinear_mfma_r14_kernel(
    const float* __restrict__ x, const float* __restrict__ W,
    const float* __restrict__ bias, float* __restrict__ out)
{
    // W A-frags: [otile][ks][lane][slot] u32 (linear; reads conflict-free)
    __shared__ __align__(16) uint32_t wfrag[8][2][64][4];   // 16 KB
    // x B-frags: [bt][512] u32, XOR-swizzled placement (8 KB)
    __shared__ __align__(16) uint32_t xfrag[4][512];        //  8 KB
    // store patch: stride 64 + XOR unit swizzle
    __shared__ __align__(16) float    patch[4][16][64];     // 16 KB

    const int bid  = blockIdx.x;
    const int n    = bid & 255;        // 0..255, varies fastest
    const int slab = bid >> 8;         // 4 slabs of S*64 = 2048 rows
    const uint32_t b_base = (uint32_t)slab * (TILE_B * S);

    const int t   = threadIdx.x;
    const int l   = t & 63;
    const int wv  = t >> 6;
    const int wr  = wv >> 1;           // b-half (0..1): bt = wr*2 + {0,1}
    const int wc  = wv & 1;            // o-half (0..1)
    const int llo = l & 15;
    const int lhi = l >> 4;

    // thread-constant pack decomposition: c = t&15 -> (ks,S,K); row = t>>4
    const int c_ks = t & 1;
    const int c_S  = (t >> 1) & 1;
    const int c_K  = (t >> 2) & 3;
    const int Upak = ((c_ks << 6) | (c_K << 4) | (t >> 4))
                   ^ ((c_K & 1) << 2) ^ (c_ks << 1);
    const int pak_off = Upak * 4 + c_S * 2;   // u32 offset within bt region

    const float4v* Xg4 = (const float4v*)x;
    float4v xrA[4], xrB[4];

#define LOADX(JT, DST)                                              \
    _Pragma("unroll")                                               \
    for (int p = 0; p < 4; ++p) {                                   \
        int idx = p * 256 + t;       /* row = idx>>4 in 0..63 */    \
        uint32_t b = b_base + (uint32_t)(JT) * TILE_B + (idx >> 4); \
        DST[p] = __builtin_nontemporal_load(                        \
                    &Xg4[b * 4096u + n * 16u + (idx & 15)]);        \
    }

    LOADX(0, xrA);                     // cold x loads FIRST: latency hides
    LOADX(1, xrB);                     // under the W staging below

    // ---- stage W_n as bf16 A-fragments with the SAME k-permutation ----
    const float4* Wn4 = (const float4*)(W + (size_t)n * DO * DI);
#pragma unroll
    for (int p = 0; p < 8; ++p) {
        int idx  = p * 256 + t;        // o = idx>>4 = p*16 + (t>>4)
        float4 f = Wn4[idx];
        int o    = idx >> 4;
        int lane = (c_K << 4) | (o & 15);
        uint2 pk = make_uint2(pack_bf16(f.x, f.y), pack_bf16(f.z, f.w));
        *(uint2*)&wfrag[o >> 4][c_ks][lane][c_S * 2] = pk;
    }

    // bias: 4 consecutive o per lane -> C operand of ks=0 MFMA
    float4v bias4[4];
#pragma unroll
    for (int ot = 0; ot < 4; ++ot)
        bias4[ot] = *(const float4v*)&bias[n * DO + wc * 64 + ot * 16 + lhi * 4];

    // frag-read base offsets (u32) for the two ks, thread-constant
    const int rd0 = (((0 << 6) | l) ^ (((l >> 4) & 1) << 2) ^ 0) * 4;
    const int rd1 = (((1 << 6) | l) ^ (((l >> 4) & 1) << 2) ^ 2) * 4;

    for (int j = 0; j < S; ++j) {
        float4v* cur = (j & 1) ? xrB : xrA;   // holds tile j

        BAR_LDS();                     // xfrag free (prev tile's reads consumed)

        // pack tile j regs -> swizzled frags (p = bt; thread-constant addr,
        // 2 touches/bank)
#pragma unroll
        for (int p = 0; p < 4; ++p) {
            uint2 pk = make_uint2(pack_bf16(cur[p][0], cur[p][1]),
                                  pack_bf16(cur[p][2], cur[p][3]));
            *(uint2*)&xfrag[p][pak_off] = pk;
        }
        if (j + 2 < S) { LOADX(j + 2, cur); }   // depth-2: 2 bodies of latency

        BAR_LDS();                     // xfrag ready (lgkmcnt(0) before bar)

        // ---- compute: D(o,b) = W_n * x^T + bias ----
        float4v acc[2][4];
#pragma unroll
        for (int ks = 0; ks < 2; ++ks) {
            short8 wf[4];
#pragma unroll
            for (int ot = 0; ot < 4; ++ot)
                wf[ot] = *(const short8*)&wfrag[wc * 4 + ot][ks][l][0];
#pragma unroll
            for (int bt = 0; bt < 2; ++bt) {
                short8 xf = *(const short8*)&xfrag[wr * 2 + bt][ks ? rd1 : rd0];
#pragma unroll
                for (int ot = 0; ot < 4; ++ot) {
                    acc[bt][ot] = __builtin_amdgcn_mfma_f32_16x16x32_bf16(
                        wf[ot], xf, (ks == 0) ? bias4[ot] : acc[bt][ot], 0, 0, 0);
                }
            }
        }

        // ---- full-line store epilogue (swizzled patch, conflict-free) ----
        // acc[bt][ot][reg]: row b = ..(wr*2+bt)*16+llo, o = wc*64+ot*16+lhi*4+reg
#pragma unroll
        for (int bt = 0; bt < 2; ++bt) {
#pragma unroll
            for (int ot = 0; ot < 4; ++ot)
                *(float4v*)&patch[wv][llo][((ot * 4 + lhi) ^ (llo & 7)) * 4] = acc[bt][ot];
            // read row-major: 16 lanes cover one row's 256B (2 full lines)
#pragma unroll
            for (int m = 0; m < 4; ++m) {
                int R = m * 4 + lhi;
                float4v v = *(const float4v*)&patch[wv][R][(llo ^ (R & 7)) * 4];
                uint32_t b = b_base + (uint32_t)j * TILE_B
                           + (uint32_t)(wr * 2 + bt) * 16 + (uint32_t)R;
                __builtin_nontemporal_store(
                    v, (float4v*)&out[b * 32768u + n * 128u + wc * 64u + llo * 4u]);
            }
        }
    }
#undef LOADX
}

extern "C" void kernel_launch(void* const* d_in, const int* in_sizes, int n_in,
                              void* d_out, int out_size, void* d_ws, size_t ws_size,
                              hipStream_t stream) {
    const float* xp = (const float*)d_in[0];
    const float* Wp = (const float*)d_in[1];
    const float* bp = (const float*)d_in[2];
    float* op = (float*)d_out;

    dim3 grid(1024);   // 256 n (fastest) * 4 slabs of 2048 rows = whole grid resident
    dim3 block(256);
    hipLaunchKernelGGL(nlinear_mfma_r14_kernel, grid, block, 0, stream, xp, Wp, bp, op);
}